// Round 10
// baseline (391.619 us; speedup 1.0000x reference)
//
#include <hip/hip_runtime.h>
#include <cstdint>
#include <cstddef>

#define BETA 5.5f
#define ALPHA 0.5f

constexpr int D   = 512;     // feature dim
constexpr int NB  = 4096;    // queries
constexpr int NK  = 16384;   // keys
constexpr int BQ  = 64;      // query tile per block
constexpr int BN  = 64;      // key chunk
constexpr int NSPLIT = 4;
constexpr int NRANGE = NK / NSPLIT;   // 4096
constexpr int CHUNKS = NRANGE / BN;   // 64
constexpr int KROW = D + 8;           // padded LDS row (bf16), 1040 B
constexpr int PROW = BN + 8;          // padded P row: 72

typedef __attribute__((ext_vector_type(8)))  short    short8;
typedef __attribute__((ext_vector_type(4)))  float    floatx4;
typedef __attribute__((ext_vector_type(4)))  uint32_t uint4v;
typedef __attribute__((ext_vector_type(2)))  uint32_t uint2v;

__device__ inline uint32_t f2bf1(float f) {
  union { float f; uint32_t u; } v; v.f = f;
  return (v.u + 0x7FFFu + ((v.u >> 16) & 1u)) >> 16;   // RNE
}
__device__ inline uint32_t pack2(float a, float b) {
  return f2bf1(a) | (f2bf1(b) << 16);
}

__device__ inline void load_lds16(const void* g, void* l) {
  __builtin_amdgcn_global_load_lds(
      (const __attribute__((address_space(1))) uint32_t*)g,
      (__attribute__((address_space(3))) uint32_t*)l, 16, 0, 0);
}

// ---------------- normalize Q -> Qn (bf16), and init out = Q ----------------
__global__ void norm_q_kernel(const float* __restrict__ q,
                              float* __restrict__ out,
                              unsigned short* __restrict__ Qn) {
  const int wave = threadIdx.x >> 6, lane = threadIdx.x & 63;
  const int row = blockIdx.x * 4 + wave;
  const float4* qr = (const float4*)(q + (size_t)row * D);
  float4 a = qr[lane * 2];
  float4 b = qr[lane * 2 + 1];
  float ss = a.x*a.x + a.y*a.y + a.z*a.z + a.w*a.w
           + b.x*b.x + b.y*b.y + b.z*b.z + b.w*b.w;
#pragma unroll
  for (int m = 32; m >= 1; m >>= 1) ss += __shfl_xor(ss, m, 64);
  const float sc = 1.0f / fmaxf(sqrtf(ss), 1e-12f);
  float4* orow = (float4*)(out + (size_t)row * D);
  orow[lane * 2]     = a;
  orow[lane * 2 + 1] = b;
  uint4v w;
  w.x = pack2(a.x*sc, a.y*sc); w.y = pack2(a.z*sc, a.w*sc);
  w.z = pack2(b.x*sc, b.y*sc); w.w = pack2(b.z*sc, b.w*sc);
  *(uint4v*)(Qn + (size_t)row * D + lane * 8) = w;
}

// ------ normalize K -> Kn (bf16 row-major) + KnT (bf16 transposed) ----------
__global__ void norm_k_kernel(const float* __restrict__ k,
                              unsigned short* __restrict__ Kn,
                              unsigned short* __restrict__ KnT) {
  __shared__ unsigned short tile[64 * KROW];
  const int wave = threadIdx.x >> 6, lane = threadIdx.x & 63;
  const int n0 = blockIdx.x * 64;
#pragma unroll
  for (int i = 0; i < 4; ++i) {
    const int rl = wave * 4 + i;
    const int n  = n0 + rl;
    const float4* kr = (const float4*)(k + (size_t)n * D);
    float4 a = kr[lane * 2], b = kr[lane * 2 + 1];
    float ss = a.x*a.x + a.y*a.y + a.z*a.z + a.w*a.w
             + b.x*b.x + b.y*b.y + b.z*b.z + b.w*b.w;
#pragma unroll
    for (int m = 32; m >= 1; m >>= 1) ss += __shfl_xor(ss, m, 64);
    const float sc = 1.0f / fmaxf(sqrtf(ss), 1e-12f);
    uint4v w;
    w.x = pack2(a.x*sc, a.y*sc); w.y = pack2(a.z*sc, a.w*sc);
    w.z = pack2(b.x*sc, b.y*sc); w.w = pack2(b.z*sc, b.w*sc);
    *(uint4v*)(Kn + (size_t)n * D + lane * 8) = w;
    *(uint4v*)&tile[rl * KROW + lane * 8]     = w;
  }
  __syncthreads();
  const int dsub = threadIdx.x >> 3;        // 0..127
  const int nl   = (threadIdx.x & 7) * 8;   // 0..56
#pragma unroll
  for (int iter = 0; iter < 4; ++iter) {
    const int d = iter * 128 + ((dsub + nl) & 127);   // rotated column (R9)
    uint4v w;
    w.x = (uint32_t)tile[(nl+0)*KROW + d] | ((uint32_t)tile[(nl+1)*KROW + d] << 16);
    w.y = (uint32_t)tile[(nl+2)*KROW + d] | ((uint32_t)tile[(nl+3)*KROW + d] << 16);
    w.z = (uint32_t)tile[(nl+4)*KROW + d] | ((uint32_t)tile[(nl+5)*KROW + d] << 16);
    w.w = (uint32_t)tile[(nl+6)*KROW + d] | ((uint32_t)tile[(nl+7)*KROW + d] << 16);
    *(uint4v*)(KnT + (size_t)d * NK + n0 + nl) = w;
  }
}

// ---------------- fused: S = Qn Kn^T chunk, P = exp, O += P Kn --------------
// v11: structural S-side rebuild on the R9 schedule.
//  * __launch_bounds__(512,1): LDS (151.5KB) already caps residency at
//    1 block/CU (2 waves/SIMD); the (512,2) VGPR cap of 256 was pure waste.
//    Now 512 VGPR/wave budget; 2x~370 fits the 2048/SIMD pool -> occupancy
//    unchanged.
//  * S-wave w owns n-rows [16w,16w+16) and ALL 64 q-cols: qf[4][16] (256
//    VGPR). Per region: 16 b128 A-reads -> 64 MFMAs (ratio 4:1, was 2:1);
//    every K row read EXACTLY once (was 2x); all 16 reads issued up-front
//    into af[16] (64 VGPR) so counted-lgkmcnt covers them under MFMA; 4
//    independent sacc chains.
//  * O-branch, staging ownership, 1-barrier/region schedule, S-prio held,
//    numerics: identical to R9.
__global__ __launch_bounds__(512, 1) void fused_kernel(
    const unsigned short* __restrict__ Qn,
    const unsigned short* __restrict__ Kn,
    const unsigned short* __restrict__ KnT,
    float* __restrict__ out) {
  __shared__ unsigned short K_lds[2][BN * KROW];   // 2 x 66.5 KB
  __shared__ unsigned short P_lds[2][BQ * PROW];   // 2 x 9.2 KB  (151.5 KB)

  const int tid  = threadIdx.x;
  const int wave = tid >> 6, lane = tid & 63;
  const int l15  = lane & 15, quad = lane >> 4;
  const int nsplit = blockIdx.x & (NSPLIT - 1);
  const int qtile  = blockIdx.x >> 2;           // 0..63
  const int q0     = qtile * BQ;
  const int nbase  = nsplit * NRANGE;

  if (wave < 4) {
    // ================= S-producer: GEMM1 + exp -> P_lds ===================
    const int sw = wave;                 // owns n-rows [16*sw, 16*sw+16)
    // Q B-fragments: ALL 64 q-cols x 512 k -> 256 VGPR (persistent)
    short8 qf[4][16];
    {
      const unsigned short* qrow0 = Qn + (size_t)(q0 + l15) * D + quad * 8;
#pragma unroll
      for (int qt = 0; qt < 4; ++qt)
#pragma unroll
        for (int kb = 0; kb < 16; ++kb)
          qf[qt][kb] = *(const short8*)(qrow0 + (size_t)qt * 16 * D + kb * 32);
    }

    floatx4 sacc[4];                     // 4 independent chains (one per qt)

    auto stage = [&](int ch, int buf) {
#pragma unroll
      for (int i = 0; i < 16; ++i) {
        const int row = sw * 16 + i;
        load_lds16(Kn + (size_t)(nbase + ch * BN + row) * D + lane * 8,
                   &K_lds[buf][row * KROW]);
      }
    };
    // A-frag for mfma(A=K,B=Q): row(n)=sw*16+l15, k=kb*32+quad*8
    auto a_read = [&](int buf, int kb) -> short8 {
      return *(const short8*)&K_lds[buf][(sw*16 + l15) * KROW + kb*32 + quad*8];
    };
    // region body: ALL 16 operand reads first, then staging DMA, then MFMA
    auto gemm1_region_st = [&](int buf, int sch, int sbuf, bool do_stage) {
#pragma unroll
      for (int qt = 0; qt < 4; ++qt) sacc[qt] = (floatx4){0.f, 0.f, 0.f, 0.f};
      short8 af[16];
#pragma unroll
      for (int kb = 0; kb < 16; ++kb) af[kb] = a_read(buf, kb);
      if (do_stage) stage(sch, sbuf);    // DMA issue after the reads
#pragma unroll
      for (int kb = 0; kb < 16; ++kb) {
        sacc[0] = __builtin_amdgcn_mfma_f32_16x16x32_bf16(af[kb], qf[0][kb], sacc[0], 0, 0, 0);
        sacc[1] = __builtin_amdgcn_mfma_f32_16x16x32_bf16(af[kb], qf[1][kb], sacc[1], 0, 0, 0);
        sacc[2] = __builtin_amdgcn_mfma_f32_16x16x32_bf16(af[kb], qf[2][kb], sacc[2], 0, 0, 0);
        sacc[3] = __builtin_amdgcn_mfma_f32_16x16x32_bf16(af[kb], qf[3][kb], sacc[3], 0, 0, 0);
      }
    };
    // C-frag: col(q)=qt*16+l15, row(n)=sw*16+quad*4+r -> P_lds[q][n]
    auto exp_pw = [&](int slot) {
#pragma unroll
      for (int qt = 0; qt < 4; ++qt) {
        const floatx4 s = sacc[qt];
        uint2v w;
        w.x = pack2(__expf(BETA * (s[0] - 1.f)), __expf(BETA * (s[1] - 1.f)));
        w.y = pack2(__expf(BETA * (s[2] - 1.f)), __expf(BETA * (s[3] - 1.f)));
        *(uint2v*)&P_lds[slot][(qt*16 + l15) * PROW + sw*16 + quad*4] = w;
      }
    };

    __builtin_amdgcn_s_setprio(1);       // producer priority, held (R9 edit a)

    // prologue
    stage(0, 0);
    asm volatile("s_waitcnt vmcnt(0)" ::: "memory");   // qf + stage(0) done
    asm volatile("s_barrier" ::: "memory");            // B0
    gemm1_region_st(0, 1, 1, true);                    // chunk 0, stage(1)
    exp_pw(0);
    asm volatile("s_waitcnt vmcnt(0) lgkmcnt(0)" ::: "memory"); // stage(1)+P(0)
    asm volatile("s_barrier" ::: "memory");            // B1

    // steady: region r computes chunk r+1 -> P_lds[(r+1)&1], stages r+2
#pragma unroll 1
    for (int r = 0; r + 2 < CHUNKS; ++r) {
      gemm1_region_st((r + 1) & 1, r + 2, r & 1, true);
      exp_pw((r + 1) & 1);
      asm volatile("s_waitcnt vmcnt(0) lgkmcnt(0)" ::: "memory");
      asm volatile("s_barrier" ::: "memory");
    }
    // tail: region CHUNKS-2 computes chunk CHUNKS-1 (no staging)
    gemm1_region_st((CHUNKS - 1) & 1, 0, 0, false);
    exp_pw((CHUNKS - 1) & 1);
    asm volatile("s_waitcnt lgkmcnt(0)" ::: "memory");
    asm volatile("s_barrier" ::: "memory");
    __builtin_amdgcn_s_setprio(0);
    // S-waves exit (O-waves' final region has no barrier)
  } else {
    // ================= O-consumer: GEMM2 + epilogue =======================
    const int w4 = wave - 4;               // d-slice [w4*128, +128)
    floatx4 oacc[4][8] = {};               // 64q x 128d
    short8 ktf[2][8];                      // 64 reg
    const unsigned short* ktb = KnT + (size_t)(w4 * 128 + l15) * NK + nbase + quad * 8;

    auto ldKT = [&](short8* kt, int c, int kb2) {
#pragma unroll
      for (int td = 0; td < 8; ++td)
        kt[td] = *(const short8*)(ktb + (size_t)td * 16 * NK + c * BN + kb2 * 32);
    };
    auto pf_read = [&](int slot, int kb2, short8* pf) {
#pragma unroll
      for (int tr = 0; tr < 4; ++tr)
        pf[tr] = *(const short8*)&P_lds[slot][(tr*16 + l15) * PROW + kb2*32 + quad*8];
    };
    auto g2c = [&](const short8* pf, const short8* kt) {
#pragma unroll
      for (int td = 0; td < 8; ++td)
#pragma unroll
        for (int tr = 0; tr < 4; ++tr)
          oacc[tr][td] = __builtin_amdgcn_mfma_f32_16x16x32_bf16(
              pf[tr], kt[td], oacc[tr][td], 0, 0, 0);
    };

    ldKT(ktf[0], 0, 0); ldKT(ktf[1], 0, 1);   // chunk 0 ktf in flight
    asm volatile("s_barrier" ::: "memory");    // B0
    asm volatile("s_barrier" ::: "memory");    // B1 (P(0) now visible)

    // steady: region r consumes P(r) x ktf(chunk r); issues ktf(r+1)
#pragma unroll 1
    for (int r = 0; r + 2 < CHUNKS; ++r) {
      short8 pf0[4], pf1[4];
      pf_read(r & 1, 0, pf0);            // both halves issued early
      pf_read(r & 1, 1, pf1);
      g2c(pf0, ktf[0]);                  // compiler waits vmcnt for ktf[0]
      ldKT(ktf[0], r + 1, 0);            // refill after last use (in-order WAR)
      g2c(pf1, ktf[1]);
      ldKT(ktf[1], r + 1, 1);
      asm volatile("s_barrier" ::: "memory");   // no waits: ktf stays in flight
    }
    // region CHUNKS-2: consume P(CHUNKS-2), issue ktf(CHUNKS-1)
    {
      const int r = CHUNKS - 2;
      short8 pf0[4], pf1[4];
      pf_read(r & 1, 0, pf0);
      pf_read(r & 1, 1, pf1);
      g2c(pf0, ktf[0]);
      ldKT(ktf[0], CHUNKS - 1, 0);
      g2c(pf1, ktf[1]);
      ldKT(ktf[1], CHUNKS - 1, 1);
      asm volatile("s_barrier" ::: "memory");
    }
    // final region: consume P(CHUNKS-1); no barrier
    {
      short8 pf0[4], pf1[4];
      pf_read((CHUNKS - 1) & 1, 0, pf0);
      pf_read((CHUNKS - 1) & 1, 1, pf1);
      g2c(pf0, ktf[0]);
      g2c(pf1, ktf[1]);
    }

    // ---- epilogue: out += ALPHA * O (out pre-init to Q) ----
    const int colbase = w4 * 128 + l15;
#pragma unroll
    for (int tr = 0; tr < 4; ++tr)
#pragma unroll
      for (int td = 0; td < 8; ++td)
#pragma unroll
        for (int r4 = 0; r4 < 4; ++r4)
          atomicAdd(out + (size_t)(q0 + tr*16 + quad*4 + r4) * D + colbase + td*16,
                    ALPHA * oacc[tr][td][r4]);
  }
}

extern "C" void kernel_launch(void* const* d_in, const int* in_sizes, int n_in,
                              void* d_out, int out_size, void* d_ws, size_t ws_size,
                              hipStream_t stream) {
  (void)in_sizes; (void)n_in; (void)out_size; (void)ws_size;
  const float* q = (const float*)d_in[0];
  const float* k = (const float*)d_in[1];
  float* out = (float*)d_out;
  unsigned short* Qn  = (unsigned short*)d_ws;          //  4 MB
  unsigned short* Kn  = Qn + (size_t)NB * D;            // 16 MB
  unsigned short* KnT = Kn + (size_t)NK * D;            // 16 MB  (total 36 MB)

  hipLaunchKernelGGL(norm_q_kernel, dim3(NB / 4),  dim3(256),  0, stream, q, out, Qn);
  hipLaunchKernelGGL(norm_k_kernel, dim3(NK / 64), dim3(1024), 0, stream, k, Kn, KnT);
  hipLaunchKernelGGL(fused_kernel, dim3((NB / BQ) * NSPLIT), dim3(512), 0, stream,
                     Qn, Kn, KnT, out);
}